// Round 2
// baseline (489.924 us; speedup 1.0000x reference)
//
#include <hip/hip_runtime.h>
#include <stdint.h>

#define BB 2
#define NN 512
#define ENF 128
#define EEF 64
#define FF 64
#define HH 8

// static scratch offsets (floats)
#define WS_NF   0         // [B*N*64]   = 65536
#define WS_Q    65536     // [B*N*8]    = 8192
#define WS_M    73728     // [64*8]     = 512   (M = edge_W @ att_W)
#define WS_EW   74240     // [64*64]    = 4096
#define WS_EB   78336     // [64]
#define WS_FLAG 78400     // [7] per-array isf32 flags (+ pad)
#define WS_WN   78464     // [B*N*N]    = 524288
#define WS_WNT  602752    // [B*N*N]    = 524288 (wnT[b,i,j] = wn[b,j,i])
#define WS_TOTAL 1127040
// flag index: 0=edges 1=nodes 2=node_W 3=node_b 4=edge_W 5=edge_b 6=att_W

__device__ float g_ws[WS_TOTAL];

__device__ __forceinline__ float bf2f(uint16_t u) {
  return __uint_as_float(((uint32_t)u) << 16);
}
__device__ __forceinline__ float load1(const void* p, size_t i, bool isf32) {
  return isf32 ? ((const float*)p)[i] : bf2f(((const uint16_t*)p)[i]);
}
__device__ __forceinline__ float elu(float x) {
  return x > 0.f ? x : expf(x) - 1.0f;
}

constexpr float INV_SQRT8 = 0.35355339059327373f;

// ------------- K0: per-array dtype detection (f32 vs bf16 in memory) -------------
__global__ __launch_bounds__(256) void k0_detect(
    const uint16_t* p0, int c0, const uint16_t* p1, int c1,
    const uint16_t* p2, int c2, const uint16_t* p3, int c3,
    const uint16_t* p4, int c4, const uint16_t* p5, int c5,
    const uint16_t* p6, int c6) {
  const uint16_t* ptrs[7] = {p0, p1, p2, p3, p4, p5, p6};
  const int cnts[7] = {c0, c1, c2, c3, c4, c5, c6};
  const int a = blockIdx.x;
  const uint16_t* e = ptrs[a];
  int S = cnts[a] / 2; if (S > 2048) S = 2048;
  const int t = threadIdx.x;
  int hi = 0, z0 = 0, nz1 = 0;
  for (int i = t; i < S; i += 256) {
    uint16_t h0 = e[2 * i], h1 = e[2 * i + 1];
    if (((h0 >> 7) & 0xFF) >= 0x90) hi++;
    if (h0 == 0) z0++;
    if (h1 != 0) nz1++;
  }
  for (int o = 32; o > 0; o >>= 1) {
    hi += __shfl_xor(hi, o); z0 += __shfl_xor(z0, o); nz1 += __shfl_xor(nz1, o);
  }
  __shared__ int r[3][4];
  if ((t & 63) == 0) { int w = t >> 6; r[0][w] = hi; r[1][w] = z0; r[2][w] = nz1; }
  __syncthreads();
  if (t == 0) {
    int H  = r[0][0] + r[0][1] + r[0][2] + r[0][3];
    int Z  = r[1][0] + r[1][1] + r[1][2] + r[1][3];
    int NZ = r[2][0] + r[2][1] + r[2][2] + r[2][3];
    g_ws[WS_FLAG + a] =
        (H > S / 16 || (Z * 8 > S * 3 && NZ * 8 > S * 3)) ? 1.0f : 0.0f;
  }
}

// ---------------- K1: nf, q (+ upcast edge_W/edge_b, M = edge_W @ att_W) ----------------
__global__ __launch_bounds__(64) void k1_nf_q(
    const void* __restrict__ nodes, const void* __restrict__ node_W,
    const void* __restrict__ node_b, const void* __restrict__ att_W,
    const void* __restrict__ edge_W, const void* __restrict__ edge_b) {
  float* nf  = g_ws + WS_NF;
  float* q   = g_ws + WS_Q;
  float* Mf  = g_ws + WS_M;
  float* eWf = g_ws + WS_EW;
  float* ebf = g_ws + WS_EB;
  const float* fl = g_ws + WS_FLAG;
  const bool fNodes = fl[1] != 0.f, fNW = fl[2] != 0.f, fNB = fl[3] != 0.f;
  const bool fEW = fl[4] != 0.f, fEB = fl[5] != 0.f, fAW = fl[6] != 0.f;
  const int bi = blockIdx.x;           // b*N + n
  const int t  = threadIdx.x;          // 0..63
  __shared__ float nd[ENF];
  __shared__ float nf_s[FF];
  nd[t]      = load1(nodes, (size_t)bi * ENF + t, fNodes);
  nd[t + 64] = load1(nodes, (size_t)bi * ENF + t + 64, fNodes);
  __syncthreads();
  float acc = load1(node_b, t, fNB);
#pragma unroll 8
  for (int e = 0; e < ENF; ++e) acc += nd[e] * load1(node_W, e * FF + t, fNW);
  nf[bi * FF + t] = acc;
  nf_s[t] = acc;
  __syncthreads();
  if (t < HH) {
    float s = 0.f;
#pragma unroll
    for (int k = 0; k < FF; ++k) s += nf_s[k] * load1(att_W, k * HH + t, fAW);
    q[bi * HH + t] = s;
  }
  if (bi == 0) {
    for (int idx = t; idx < EEF * FF; idx += 64)
      eWf[idx] = load1(edge_W, idx, fEW);
    ebf[t] = load1(edge_b, t, fEB);
    // M[c][h] = sum_k edge_W[c,k] * att_W[k,h]   (thread t owns row c = t)
    float mrow[HH];
#pragma unroll
    for (int h = 0; h < HH; ++h) mrow[h] = 0.f;
    for (int k = 0; k < FF; ++k) {
      float w = load1(edge_W, t * FF + k, fEW);
#pragma unroll
      for (int h = 0; h < HH; ++h) mrow[h] += w * load1(att_W, k * HH + h, fAW);
    }
#pragma unroll
    for (int h = 0; h < HH; ++h) Mf[t * HH + h] = mrow[h];
  }
}

// ---------------- K2: wn = softmax_j( q_i . q_j / sqrt(8) ), + transposed copy ----------------
__global__ __launch_bounds__(256) void k2_wn() {
  const float* ws_q = g_ws + WS_Q;
  float* wn  = g_ws + WS_WN;
  float* wnT = g_ws + WS_WNT;
  const int bi = blockIdx.x;          // b*N + i
  const int b  = bi >> 9, i = bi & 511;
  const int t  = threadIdx.x;
  __shared__ float red[4];
  __shared__ float red2[4];
  const float* qi = ws_q + bi * HH;
  const float q0 = qi[0], q1 = qi[1], q2 = qi[2], q3 = qi[3];
  const float q4 = qi[4], q5 = qi[5], q6 = qi[6], q7 = qi[7];
  const float* qb = ws_q + ((size_t)(b << 9)) * HH;
  const int j0 = t, j1 = t + 256;
  const float* qa = qb + j0 * HH;
  float s0 = (q0*qa[0]+q1*qa[1]+q2*qa[2]+q3*qa[3]+q4*qa[4]+q5*qa[5]+q6*qa[6]+q7*qa[7]) * INV_SQRT8;
  const float* qc = qb + j1 * HH;
  float s1 = (q0*qc[0]+q1*qc[1]+q2*qc[2]+q3*qc[3]+q4*qc[4]+q5*qc[5]+q6*qc[6]+q7*qc[7]) * INV_SQRT8;
  float m = fmaxf(s0, s1);
  for (int o = 32; o > 0; o >>= 1) m = fmaxf(m, __shfl_xor(m, o));
  if ((t & 63) == 0) red[t >> 6] = m;
  __syncthreads();
  m = fmaxf(fmaxf(red[0], red[1]), fmaxf(red[2], red[3]));
  float p0 = expf(s0 - m), p1 = expf(s1 - m);
  float s = p0 + p1;
  for (int o = 32; o > 0; o >>= 1) s += __shfl_xor(s, o);
  if ((t & 63) == 0) red2[t >> 6] = s;
  __syncthreads();
  float inv = 1.0f / (red2[0] + red2[1] + red2[2] + red2[3]);
  float* wrow = wn + (size_t)bi * NN;
  const float w0 = p0 * inv, w1 = p1 * inv;
  wrow[j0] = w0;
  wrow[j1] = w1;
  wnT[((size_t)(b << 9) + j0) * NN + i] = w0;   // scattered; L2-absorbed (2 MB)
  wnT[((size_t)(b << 9) + j1) * NN + i] = w1;
}

// ---------------- K4: lane=column GEMM (weights in VGPRs), score-first softmax,
//                  edge epilogue, aef per-lane accum, awn folded in (wnT stream) ---------------
__global__ __launch_bounds__(256, 4) void k4_main(
    const void* __restrict__ edges, float* __restrict__ out) {
  const float* nf  = g_ws + WS_NF;
  const float* qws = g_ws + WS_Q;
  const float* wn  = g_ws + WS_WN;
  const float* wnT = g_ws + WS_WNT;
  const float* eWf = g_ws + WS_EW;
  const float* ebf = g_ws + WS_EB;
  const float* Mf  = g_ws + WS_M;
  const bool isf32 = g_ws[WS_FLAG + 0] != 0.0f;
  const int bi = blockIdx.x;               // b*N + i
  const int t  = threadIdx.x;              // 0..255
  const int lane = t & 63;                 // output column k
  const int wv = __builtin_amdgcn_readfirstlane(t) >> 6;   // wave id 0..3 (SGPR)

  __shared__ float se_s[NN];               // scores, then exp(p)
  __shared__ float wn_s[NN];
  __shared__ float u_s[EEF];
  __shared__ float red[4];
  __shared__ float red2[4];
  __shared__ float red_n[4][FF];
  __shared__ float red_e[4][FF];

  // ---- setup: per-lane weight column in VGPRs, nf_i, eb, wn row stage, u ----
  const float nf_i = nf[bi * FF + lane];
  const float eb_l = ebf[lane];
  float w[EEF];
#pragma unroll
  for (int e = 0; e < EEF; ++e) w[e] = eWf[e * FF + lane];   // coalesced across lanes
  wn_s[t]       = wn[(size_t)bi * NN + t];
  wn_s[t + 256] = wn[(size_t)bi * NN + t + 256];
  if (t < EEF) {
    const float* qi = qws + bi * HH;       // uniform -> s_load
    const float* mr = Mf + t * HH;
    float s = 0.f;
#pragma unroll
    for (int h = 0; h < HH; ++h) s += mr[h] * qi[h];
    u_s[t] = s * INV_SQRT8;                // u = (edge_W @ att_W @ q_i)/sqrt(8)
  }
  __syncthreads();

  // ---- pass A: se_j = e_row_j . u  (lane-sliced vector loads, HBM-facing) ----
  if (isf32) {
    float u4[4];
#pragma unroll
    for (int c = 0; c < 4; ++c) u4[c] = u_s[4 * (lane & 15) + c];
    const float4* ep = (const float4*)edges + ((size_t)bi * NN) * 16;
#pragma unroll 4
    for (int it = 0; it < 32; ++it) {
      const int row = wv * 128 + it * 4 + (lane >> 4);
      float4 x = ep[(size_t)row * 16 + (lane & 15)];
      float p = x.x * u4[0] + x.y * u4[1] + x.z * u4[2] + x.w * u4[3];
      p += __shfl_xor(p, 1); p += __shfl_xor(p, 2);
      p += __shfl_xor(p, 4); p += __shfl_xor(p, 8);
      if ((lane & 15) == 0) se_s[row] = p;
    }
  } else {
    float u8[8];
#pragma unroll
    for (int c = 0; c < 8; ++c) u8[c] = u_s[8 * (lane & 7) + c];
    const uint4* ep = (const uint4*)edges + ((size_t)bi * NN) * 8;
#pragma unroll 4
    for (int it = 0; it < 16; ++it) {
      const int row = wv * 128 + it * 8 + (lane >> 3);
      uint4 x = ep[(size_t)row * 8 + (lane & 7)];
      float p = __uint_as_float(x.x << 16)          * u8[0]
              + __uint_as_float(x.x & 0xFFFF0000u)  * u8[1]
              + __uint_as_float(x.y << 16)          * u8[2]
              + __uint_as_float(x.y & 0xFFFF0000u)  * u8[3]
              + __uint_as_float(x.z << 16)          * u8[4]
              + __uint_as_float(x.z & 0xFFFF0000u)  * u8[5]
              + __uint_as_float(x.w << 16)          * u8[6]
              + __uint_as_float(x.w & 0xFFFF0000u)  * u8[7];
      p += __shfl_xor(p, 1); p += __shfl_xor(p, 2); p += __shfl_xor(p, 4);
      if ((lane & 7) == 0) se_s[row] = p;
    }
  }
  __syncthreads();

  // ---- softmax over 512 j ----
  float s0 = se_s[t], s1 = se_s[t + 256];
  float m = fmaxf(s0, s1);
  for (int o = 32; o > 0; o >>= 1) m = fmaxf(m, __shfl_xor(m, o));
  if (lane == 0) red[wv] = m;
  __syncthreads();
  m = fmaxf(fmaxf(red[0], red[1]), fmaxf(red[2], red[3]));
  float p0 = expf(s0 - m), p1 = expf(s1 - m);
  float ssum = p0 + p1;
  for (int o = 32; o > 0; o >>= 1) ssum += __shfl_xor(ssum, o);
  if (lane == 0) red2[wv] = ssum;
  __syncthreads();
  const float inv_tot = 1.0f / (red2[0] + red2[1] + red2[2] + red2[3]);
  se_s[t] = p0; se_s[t + 256] = p1;
  __syncthreads();

  // ---- pass B: per-row GEMM (weights in VGPR, activations wave-uniform -> s_load),
  //      fused edge epilogue + aef accumulation. FMA order over e matches prior kernel. ----
  float aef_acc = 0.f;
  float* oute = out + 65536 + ((size_t)bi * NN) * EEF;
  if (isf32) {
    const float* rp0 = (const float*)edges + ((size_t)bi * NN) * EEF;
#pragma unroll 2
    for (int rr = 0; rr < 128; ++rr) {
      const int r = wv * 128 + rr;
      const float* rp = rp0 + (size_t)r * EEF;        // wave-uniform row
      float acc = eb_l;
#pragma unroll
      for (int e = 0; e < EEF; ++e) acc = fmaf(rp[e], w[e], acc);
      const float we_r = se_s[r] * inv_tot;
      const float o = elu(acc * (1.0f + we_r) + wn_s[r] * nf_i);
      oute[(size_t)r * EEF + lane] = o;
      aef_acc = fmaf(we_r, acc, aef_acc);
    }
  } else {
    const uint32_t* rp0 = (const uint32_t*)edges + ((size_t)bi * NN) * 32;
#pragma unroll 2
    for (int rr = 0; rr < 128; ++rr) {
      const int r = wv * 128 + rr;
      const uint32_t* rp = rp0 + (size_t)r * 32;      // wave-uniform row
      float acc = eb_l;
#pragma unroll
      for (int c = 0; c < 32; ++c) {
        const uint32_t d = rp[c];
        acc = fmaf(__uint_as_float(d << 16),         w[2 * c],     acc);
        acc = fmaf(__uint_as_float(d & 0xFFFF0000u), w[2 * c + 1], acc);
      }
      const float we_r = se_s[r] * inv_tot;
      const float o = elu(acc * (1.0f + we_r) + wn_s[r] * nf_i);
      oute[(size_t)r * EEF + lane] = o;
      aef_acc = fmaf(we_r, acc, aef_acc);
    }
  }

  // ---- awn[b,i,k] = sum_j wnT[b,i,j] * nf[b,j,k]  (scalar wnT stream, folded k3) ----
  float awn_acc = 0.f;
  {
    const float* wtrow = wnT + (size_t)bi * NN;                 // uniform, contiguous
    const float* nfb   = nf + (size_t)((bi >> 9) << 9) * FF;    // batch base
#pragma unroll 8
    for (int jj = 0; jj < 128; ++jj) {
      const int j = wv * 128 + jj;
      awn_acc = fmaf(wtrow[j], nfb[(size_t)j * FF + lane], awn_acc);
    }
  }
  red_n[wv][lane] = awn_acc;
  red_e[wv][lane] = aef_acc;
  __syncthreads();

  // ---- node output (f32) ----
  if (t < FF) {
    float sum = nf_i
              + red_n[0][t] + red_n[1][t] + red_n[2][t] + red_n[3][t]
              + red_e[0][t] + red_e[1][t] + red_e[2][t] + red_e[3][t];
    out[bi * FF + t] = elu(sum);
  }
}

extern "C" void kernel_launch(void* const* d_in, const int* in_sizes, int n_in,
                              void* d_out, int out_size, void* d_ws, size_t ws_size,
                              hipStream_t stream) {
  // Identify inputs by element count (robust to mask-dropping / reordering).
  const void* nodes = nullptr; const void* edges = nullptr;
  const void* node_W = nullptr; const void* node_b = nullptr;
  const void* edge_W = nullptr; const void* edge_b = nullptr;
  const void* att_W = nullptr;
  int bias_seen = 0;
  for (int i = 0; i < n_in; ++i) {
    switch (in_sizes[i]) {
      case 33554432: edges  = d_in[i]; break;
      case 131072:   nodes  = d_in[i]; break;
      case 8192:     node_W = d_in[i]; break;
      case 4096:     edge_W = d_in[i]; break;
      case 512:      att_W  = d_in[i]; break;
      case 64:       if (bias_seen++ == 0) node_b = d_in[i]; else edge_b = d_in[i]; break;
      default: break;  // mask or scalars: unused
    }
  }
  float* out = (float*)d_out;

  k0_detect<<<dim3(7), dim3(256), 0, stream>>>(
      (const uint16_t*)edges, 33554432, (const uint16_t*)nodes, 131072,
      (const uint16_t*)node_W, 8192, (const uint16_t*)node_b, 64,
      (const uint16_t*)edge_W, 4096, (const uint16_t*)edge_b, 64,
      (const uint16_t*)att_W, 512);
  k1_nf_q<<<dim3(BB * NN), dim3(64), 0, stream>>>(nodes, node_W, node_b,
                                                  att_W, edge_W, edge_b);
  k2_wn<<<dim3(BB * NN), dim3(256), 0, stream>>>();
  k4_main<<<dim3(BB * NN), dim3(256), 0, stream>>>(edges, out);
}

// Round 3
// 416.406 us; speedup vs baseline: 1.1766x; 1.1766x over previous
//
#include <hip/hip_runtime.h>
#include <stdint.h>

#define BB 2
#define NN 512
#define ENF 128
#define EEF 64
#define FF 64
#define HH 8

// static scratch offsets (floats)
#define WS_NF    0        // [B*N*64]   = 65536
#define WS_Q     65536    // [B*N*8]    = 8192
#define WS_V     73728    // [B*N*64]   = 65536  (v = att_W@q * 1/sqrt(8))
#define WS_EW    139264   // [64*64]    = 4096
#define WS_EB    143360   // [64]
#define WS_STATS 143424   // [B*N*2]    = 2048   (m, 1/S per node row)
#define WS_FLAG  145472   // [7] per-array isf32 flags
#define WS_TOTAL 145480
// flag index: 0=edges 1=nodes 2=node_W 3=node_b 4=edge_W 5=edge_b 6=att_W

__device__ float g_ws[WS_TOTAL];

__device__ __forceinline__ float bf2f(uint16_t u) {
  return __uint_as_float(((uint32_t)u) << 16);
}
__device__ __forceinline__ float load1(const void* p, size_t i, bool isf32) {
  return isf32 ? ((const float*)p)[i] : bf2f(((const uint16_t*)p)[i]);
}
__device__ __forceinline__ float elu(float x) {
  return x > 0.f ? x : expf(x) - 1.0f;
}

constexpr float INV_SQRT8 = 0.35355339059327373f;

// ------------- K0: per-array dtype detection (f32 vs bf16 in memory) -------------
__global__ __launch_bounds__(256) void k0_detect(
    const uint16_t* p0, int c0, const uint16_t* p1, int c1,
    const uint16_t* p2, int c2, const uint16_t* p3, int c3,
    const uint16_t* p4, int c4, const uint16_t* p5, int c5,
    const uint16_t* p6, int c6) {
  const uint16_t* ptrs[7] = {p0, p1, p2, p3, p4, p5, p6};
  const int cnts[7] = {c0, c1, c2, c3, c4, c5, c6};
  const int a = blockIdx.x;
  const uint16_t* e = ptrs[a];
  int S = cnts[a] / 2; if (S > 2048) S = 2048;
  const int t = threadIdx.x;
  int hi = 0, z0 = 0, nz1 = 0;
  for (int i = t; i < S; i += 256) {
    uint16_t h0 = e[2 * i], h1 = e[2 * i + 1];
    if (((h0 >> 7) & 0xFF) >= 0x90) hi++;
    if (h0 == 0) z0++;
    if (h1 != 0) nz1++;
  }
  for (int o = 32; o > 0; o >>= 1) {
    hi += __shfl_xor(hi, o); z0 += __shfl_xor(z0, o); nz1 += __shfl_xor(nz1, o);
  }
  __shared__ int r[3][4];
  if ((t & 63) == 0) { int w = t >> 6; r[0][w] = hi; r[1][w] = z0; r[2][w] = nz1; }
  __syncthreads();
  if (t == 0) {
    int H  = r[0][0] + r[0][1] + r[0][2] + r[0][3];
    int Z  = r[1][0] + r[1][1] + r[1][2] + r[1][3];
    int NZ = r[2][0] + r[2][1] + r[2][2] + r[2][3];
    g_ws[WS_FLAG + a] =
        (H > S / 16 || (Z * 8 > S * 3 && NZ * 8 > S * 3)) ? 1.0f : 0.0f;
  }
}

// ---------------- K1: nf, q, v (+ upcast edge_W/edge_b) ----------------
__global__ __launch_bounds__(64) void k1_nf_q_v(
    const void* __restrict__ nodes, const void* __restrict__ node_W,
    const void* __restrict__ node_b, const void* __restrict__ att_W,
    const void* __restrict__ edge_W, const void* __restrict__ edge_b) {
  float* nf  = g_ws + WS_NF;
  float* q   = g_ws + WS_Q;
  float* v   = g_ws + WS_V;
  float* eWf = g_ws + WS_EW;
  float* ebf = g_ws + WS_EB;
  const float* fl = g_ws + WS_FLAG;
  const bool fNodes = fl[1] != 0.f, fNW = fl[2] != 0.f, fNB = fl[3] != 0.f;
  const bool fEW = fl[4] != 0.f, fEB = fl[5] != 0.f, fAW = fl[6] != 0.f;
  const int bi = blockIdx.x;           // b*N + n
  const int t  = threadIdx.x;          // 0..63
  __shared__ float nd[ENF];
  __shared__ float nf_s[FF];
  __shared__ float q_s[HH];
  nd[t]      = load1(nodes, (size_t)bi * ENF + t, fNodes);
  nd[t + 64] = load1(nodes, (size_t)bi * ENF + t + 64, fNodes);
  __syncthreads();
  float acc = load1(node_b, t, fNB);
#pragma unroll 8
  for (int e = 0; e < ENF; ++e) acc += nd[e] * load1(node_W, e * FF + t, fNW);
  nf[bi * FF + t] = acc;
  nf_s[t] = acc;
  __syncthreads();
  if (t < HH) {
    float s = 0.f;
#pragma unroll
    for (int k = 0; k < FF; ++k) s += nf_s[k] * load1(att_W, k * HH + t, fAW);
    q[bi * HH + t] = s;
    q_s[t] = s;
  }
  __syncthreads();
  {
    float s = 0.f;
#pragma unroll
    for (int h = 0; h < HH; ++h) s += load1(att_W, t * HH + h, fAW) * q_s[h];
    v[bi * FF + t] = s * INV_SQRT8;    // fold 1/sqrt(D_EDGE)
  }
  if (bi == 0) {
    for (int idx = t; idx < EEF * FF; idx += 64)
      eWf[idx] = load1(edge_W, idx, fEW);
    ebf[t] = load1(edge_b, t, fEB);
  }
}

// ---------------- K2s: per-node-row softmax stats (m, 1/S) ----------------
// sn[i,j] = q_i.q_j/sqrt(8) is symmetric; k4 regenerates both wn row & column
// from q + these stats, so no wn matrix is ever materialized.
__global__ __launch_bounds__(256) void k2_stats() {
  const float* ws_q = g_ws + WS_Q;
  float* st = g_ws + WS_STATS;
  const int bi = blockIdx.x;          // b*N + i
  const int b  = bi >> 9;
  const int t  = threadIdx.x;
  __shared__ float red[4];
  __shared__ float red2[4];
  const float* qi = ws_q + bi * HH;
  const float q0 = qi[0], q1 = qi[1], q2 = qi[2], q3 = qi[3];
  const float q4 = qi[4], q5 = qi[5], q6 = qi[6], q7 = qi[7];
  const float* qb = ws_q + ((size_t)(b << 9)) * HH;
  const int j0 = t, j1 = t + 256;
  const float* qa = qb + j0 * HH;
  float s0 = (q0*qa[0]+q1*qa[1]+q2*qa[2]+q3*qa[3]+q4*qa[4]+q5*qa[5]+q6*qa[6]+q7*qa[7]) * INV_SQRT8;
  const float* qc = qb + j1 * HH;
  float s1 = (q0*qc[0]+q1*qc[1]+q2*qc[2]+q3*qc[3]+q4*qc[4]+q5*qc[5]+q6*qc[6]+q7*qc[7]) * INV_SQRT8;
  float m = fmaxf(s0, s1);
  for (int o = 32; o > 0; o >>= 1) m = fmaxf(m, __shfl_xor(m, o));
  if ((t & 63) == 0) red[t >> 6] = m;
  __syncthreads();
  m = fmaxf(fmaxf(red[0], red[1]), fmaxf(red[2], red[3]));
  float p0 = expf(s0 - m), p1 = expf(s1 - m);
  float s = p0 + p1;
  for (int o = 32; o > 0; o >>= 1) s += __shfl_xor(s, o);
  if ((t & 63) == 0) red2[t >> 6] = s;
  __syncthreads();
  if (t == 0) {
    st[bi * 2]     = m;
    st[bi * 2 + 1] = 1.0f / (red2[0] + red2[1] + red2[2] + red2[3]);
  }
}

// ---------------- K4: single edges pass. LDS-staged edge_W (ds_read broadcast
// instead of the SGPR-starved s_load stream), in-kernel wn row+col, edge
// softmax + epilogue, aef butterfly, awn fold (replaces k3). ----------------
__global__ __launch_bounds__(512) void k4_main(
    const void* __restrict__ edges, float* __restrict__ out) {
  const float* nf  = g_ws + WS_NF;
  const float* qws = g_ws + WS_Q;
  const float* vws = g_ws + WS_V;
  const float* ebf = g_ws + WS_EB;
  const float* st  = g_ws + WS_STATS;
  const bool isf32 = g_ws[WS_FLAG + 0] != 0.0f;
  const int bi = blockIdx.x;          // b*N + i
  const int t  = threadIdx.x;         // 0..511 == j
  const int lane = t & 63;
  const int w8 = t >> 6;

  __shared__ float eW_s[EEF * FF];    // 16 KB
  __shared__ float nfi_s[FF];
  __shared__ float wcol_s[NN];        // wn[:, i] column weights
  __shared__ float red[8];
  __shared__ float red2[8];
  __shared__ float aef_w[8][FF];
  __shared__ float awn_w[8][FF];

  // ---- stage edge_W into LDS (1024 float4 by 512 threads) ----
  {
    const float4* src = (const float4*)(g_ws + WS_EW);
    float4* dst = (float4*)eW_s;
    dst[t]       = src[t];
    dst[t + 512] = src[t + 512];
  }
  if (t < FF) nfi_s[t] = nf[bi * FF + t];

  // ---- node scores from q (symmetric sn): wn row + wn column ----
  const float m_i   = st[bi * 2];        // uniform -> s_load
  const float inv_i = st[bi * 2 + 1];
  const float* qi = qws + bi * HH;       // uniform -> s_load
  const float q0 = qi[0], q1 = qi[1], q2 = qi[2], q3 = qi[3];
  const float q4 = qi[4], q5 = qi[5], q6 = qi[6], q7 = qi[7];
  const int bbase = (bi >> 9) << 9;      // b*512
  const float* qt = qws + ((size_t)(bbase + t)) * HH;   // vector, coalesced
  const float s_t = (q0*qt[0]+q1*qt[1]+q2*qt[2]+q3*qt[3]
                    +q4*qt[4]+q5*qt[5]+q6*qt[6]+q7*qt[7]) * INV_SQRT8;
  const float wn_t = expf(s_t - m_i) * inv_i;           // wn[i, t]
  const float2 stt = ((const float2*)st)[bbase + t];    // (m_t, 1/S_t)
  wcol_s[t] = expf(s_t - stt.x) * stt.y;                // wn[t, i]
  __syncthreads();

  // ---- ef GEMM: row j = t, acc[64]; edges row pre-issued; weights via LDS ----
  const size_t row = ((size_t)bi * NN + t) * EEF;
  float acc[EEF];
#pragma unroll
  for (int k = 0; k < EEF; ++k) acc[k] = ebf[k];        // uniform -> s_load
  if (isf32) {
    const float4* epf = (const float4*)((const float*)edges + row);
#pragma unroll 1
    for (int c = 0; c < 8; ++c) {
      float4 u = epf[2 * c], w2 = epf[2 * c + 1];
      const float a0 = u.x,  a1 = u.y,  a2 = u.z,  a3 = u.w;
      const float a4 = w2.x, a5 = w2.y, a6 = w2.z, a7 = w2.w;
      const float* w = eW_s + c * 8 * FF;               // LDS broadcast reads
#pragma unroll
      for (int k = 0; k < FF; ++k) {
        float s = acc[k];
        s = fmaf(a0, w[k],        s);
        s = fmaf(a1, w[FF + k],   s);
        s = fmaf(a2, w[2*FF + k], s);
        s = fmaf(a3, w[3*FF + k], s);
        s = fmaf(a4, w[4*FF + k], s);
        s = fmaf(a5, w[5*FF + k], s);
        s = fmaf(a6, w[6*FF + k], s);
        s = fmaf(a7, w[7*FF + k], s);
        acc[k] = s;
      }
    }
  } else {
    const uint4* epb = (const uint4*)((const uint16_t*)edges + row);
    uint4 x[8];
#pragma unroll
    for (int c = 0; c < 8; ++c) x[c] = epb[c];          // 8 loads in flight
#pragma unroll 1
    for (int c = 0; c < 8; ++c) {
      const float a0 = __uint_as_float(x[c].x << 16);
      const float a1 = __uint_as_float(x[c].x & 0xFFFF0000u);
      const float a2 = __uint_as_float(x[c].y << 16);
      const float a3 = __uint_as_float(x[c].y & 0xFFFF0000u);
      const float a4 = __uint_as_float(x[c].z << 16);
      const float a5 = __uint_as_float(x[c].z & 0xFFFF0000u);
      const float a6 = __uint_as_float(x[c].w << 16);
      const float a7 = __uint_as_float(x[c].w & 0xFFFF0000u);
      const float* w = eW_s + c * 8 * FF;               // LDS broadcast reads
#pragma unroll
      for (int k = 0; k < FF; ++k) {
        float s = acc[k];
        s = fmaf(a0, w[k],        s);
        s = fmaf(a1, w[FF + k],   s);
        s = fmaf(a2, w[2*FF + k], s);
        s = fmaf(a3, w[3*FF + k], s);
        s = fmaf(a4, w[4*FF + k], s);
        s = fmaf(a5, w[5*FF + k], s);
        s = fmaf(a6, w[6*FF + k], s);
        s = fmaf(a7, w[7*FF + k], s);
        acc[k] = s;
      }
    }
  }

  // ---- se_j = ef_j . v_i (v has 1/sqrt(8) folded) ----
  const float* vi = vws + bi * FF;                      // uniform -> s_load
  float se = 0.f;
#pragma unroll
  for (int k = 0; k < EEF; ++k) se += acc[k] * vi[k];

  // ---- softmax over 512 j (one value per thread) ----
  float m = se;
  for (int o = 32; o > 0; o >>= 1) m = fmaxf(m, __shfl_xor(m, o));
  if (lane == 0) red[w8] = m;
  __syncthreads();
  m = red[0];
#pragma unroll
  for (int w = 1; w < 8; ++w) m = fmaxf(m, red[w]);
  float p = expf(se - m);
  float s = p;
  for (int o = 32; o > 0; o >>= 1) s += __shfl_xor(s, o);
  if (lane == 0) red2[w8] = s;
  __syncthreads();
  float tot = red2[0];
#pragma unroll
  for (int w = 1; w < 8; ++w) tot += red2[w];
  const float we = p / tot;

  // ---- edge epilogue (f32 stores) + we*ef for aef ----
  const float onewe = 1.0f + we;
  float4* orow = (float4*)(out + 65536 + ((size_t)bi * NN + t) * EEF);
#pragma unroll
  for (int c = 0; c < 16; ++c) {
    float4 o;
    o.x = elu(acc[4*c]   * onewe + wn_t * nfi_s[4*c]);
    o.y = elu(acc[4*c+1] * onewe + wn_t * nfi_s[4*c+1]);
    o.z = elu(acc[4*c+2] * onewe + wn_t * nfi_s[4*c+2]);
    o.w = elu(acc[4*c+3] * onewe + wn_t * nfi_s[4*c+3]);
    orow[c] = o;
    acc[4*c]   *= we;
    acc[4*c+1] *= we;
    acc[4*c+2] *= we;
    acc[4*c+3] *= we;
  }

  // ---- butterfly-reduce we*ef over the 64 lanes of each wave ----
#pragma unroll
  for (int k = 0; k < EEF; ++k) {
    float g = acc[k];
    g += __shfl_xor(g, 32);
    g += __shfl_xor(g, 16);
    g += __shfl_xor(g, 8);
    g += __shfl_xor(g, 4);
    g += __shfl_xor(g, 2);
    g += __shfl_xor(g, 1);
    acc[k] = g;
  }
  if (lane == 0) {
#pragma unroll
    for (int k = 0; k < EEF; ++k) aef_w[w8][k] = acc[k];
  }

  // ---- awn[b,i,k] = sum_j wn[b,j,i]*nf[b,j,k]  (folded k3; nf is L2-hot) ----
  float awn_acc = 0.f;
  {
    const float* nfb = nf + (size_t)bbase * FF;
#pragma unroll 8
    for (int jj = 0; jj < 64; ++jj) {
      const int j = w8 * 64 + jj;
      awn_acc = fmaf(wcol_s[j], nfb[(size_t)j * FF + lane], awn_acc);
    }
  }
  awn_w[w8][lane] = awn_acc;
  __syncthreads();

  // ---- node output (f32) ----
  if (t < FF) {
    float sum = nfi_s[t];
#pragma unroll
    for (int w = 0; w < 8; ++w) sum += aef_w[w][t] + awn_w[w][t];
    out[bi * FF + t] = elu(sum);
  }
}

extern "C" void kernel_launch(void* const* d_in, const int* in_sizes, int n_in,
                              void* d_out, int out_size, void* d_ws, size_t ws_size,
                              hipStream_t stream) {
  // Identify inputs by element count (robust to mask-dropping / reordering).
  const void* nodes = nullptr; const void* edges = nullptr;
  const void* node_W = nullptr; const void* node_b = nullptr;
  const void* edge_W = nullptr; const void* edge_b = nullptr;
  const void* att_W = nullptr;
  int bias_seen = 0;
  for (int i = 0; i < n_in; ++i) {
    switch (in_sizes[i]) {
      case 33554432: edges  = d_in[i]; break;
      case 131072:   nodes  = d_in[i]; break;
      case 8192:     node_W = d_in[i]; break;
      case 4096:     edge_W = d_in[i]; break;
      case 512:      att_W  = d_in[i]; break;
      case 64:       if (bias_seen++ == 0) node_b = d_in[i]; else edge_b = d_in[i]; break;
      default: break;  // mask or scalars: unused
    }
  }
  float* out = (float*)d_out;

  k0_detect<<<dim3(7), dim3(256), 0, stream>>>(
      (const uint16_t*)edges, 33554432, (const uint16_t*)nodes, 131072,
      (const uint16_t*)node_W, 8192, (const uint16_t*)node_b, 64,
      (const uint16_t*)edge_W, 4096, (const uint16_t*)edge_b, 64,
      (const uint16_t*)att_W, 512);
  k1_nf_q_v<<<dim3(BB * NN), dim3(64), 0, stream>>>(nodes, node_W, node_b,
                                                    att_W, edge_W, edge_b);
  k2_stats<<<dim3(BB * NN), dim3(256), 0, stream>>>();
  k4_main<<<dim3(BB * NN), dim3(512), 0, stream>>>(edges, out);
}